// Round 14
// baseline (168.823 us; speedup 1.0000x reference)
//
#include <hip/hip_runtime.h>
#include <hip/hip_bf16.h>
#include <stdint.h>

// Problem constants
#define B_  4096
#define T_  80
#define E_  100
#define U_  64
#define G_  256    // 4*U
#define V_  10000

#define S_H  72    // hbuf row stride (bf16): 144B rows
#define AS   136   // embk emb-tile LDS stride (bf16)
#define KS2  132   // embk k1-tile ROW-major LDS stride (bf16)
#define TS   81    // token LDS row stride (ints)
#define XS   260   // xstage row stride (floats)

typedef __attribute__((ext_vector_type(8))) __bf16 bf16x8;
typedef __attribute__((ext_vector_type(4))) __bf16 bf16x4;
typedef __attribute__((ext_vector_type(4))) float  floatx4;

__device__ __forceinline__ float sigmoidf_(float x) {
    return __builtin_amdgcn_rcpf(1.f + __expf(-x));
}

__device__ __forceinline__ float tanhf_(float x) {
    // 1 - 2/(e^{2x}+1): monotone, saturates correctly, no NaN
    return fmaf(-2.f, __builtin_amdgcn_rcpf(__expf(2.f * x) + 1.f), 1.f);
}

// global -> LDS direct DMA: each lane contributes 16B; LDS dest = wave-uniform
// base + lane*16 (linear). Tracked by vmcnt.
__device__ __forceinline__ void gload16(const float* gsrc, const float* ldst) {
    __builtin_amdgcn_global_load_lds(
        (const __attribute__((address_space(1))) void*)(uintptr_t)gsrc,
        (__attribute__((address_space(3))) void*)(uintptr_t)ldst,
        16, 0, 0);
}

#define MFMA16(A,B,C) __builtin_amdgcn_mfma_f32_16x16x32_bf16(A, B, C, 0, 0, 0)

// ---------------------------------------------------------------------------
// Kernel A (MFMA): embk[v][g] = b1[g] + emb[v] . k1[:,g]   (R5/R6, known-good)
// ---------------------------------------------------------------------------
__global__ __launch_bounds__(256) void embk_kernel(const float* __restrict__ emb,
                                                   const float* __restrict__ k1,
                                                   const float* __restrict__ b1,
                                                   float* __restrict__ embk) {
    __shared__ __bf16 aLDS[64 * AS];         // 17.4 KB  (emb tile, row-major)
    __shared__ __bf16 kLDS[128 * KS2];       // 33.8 KB  (k1 tile, ROW-major [k][col])

    const int tid  = threadIdx.x;
    const int lane = tid & 63;
    const int w    = tid >> 6;
    const int n    = lane & 15;
    const int kg   = lane >> 4;
    const int v0   = (blockIdx.x >> 1) * 64;
    const int n0   = (blockIdx.x & 1) * 128;
    const int nrows = min(64, V_ - v0);

    for (int i = tid; i < 64 * AS / 8; i += 256) {
        bf16x8 z;
#pragma unroll
        for (int jj = 0; jj < 8; ++jj) z[jj] = (__bf16)0.f;
        *(bf16x8*)(aLDS + i * 8) = z;
    }
    for (int i = tid; i < 28 * KS2; i += 256)
        kLDS[100 * KS2 + i] = (__bf16)0.f;

    const float bv0 = b1[n0 + w * 32 + n];
    const float bv1 = b1[n0 + w * 32 + 16 + n];

    __syncthreads();

    for (int i = tid; i < nrows * 25; i += 256) {
        int r = i / 25, q = i - r * 25;
        float4 ev = *(const float4*)(emb + (long)(v0 + r) * E_ + q * 4);
        bf16x4 bv; bv[0] = (__bf16)ev.x; bv[1] = (__bf16)ev.y;
                   bv[2] = (__bf16)ev.z; bv[3] = (__bf16)ev.w;
        *(bf16x4*)(aLDS + r * AS + q * 4) = bv;
    }
    for (int i = tid; i < 100 * 32; i += 256) {
        int k = i >> 5, cq = (i & 31) * 4;
        float4 kv = *(const float4*)(k1 + (long)k * G_ + n0 + cq);
        bf16x4 bv; bv[0] = (__bf16)kv.x; bv[1] = (__bf16)kv.y;
                   bv[2] = (__bf16)kv.z; bv[3] = (__bf16)kv.w;
        *(bf16x4*)(kLDS + k * KS2 + cq) = bv;
    }
    __syncthreads();

    bf16x8 bfr[2][4];
#pragma unroll
    for (int ct = 0; ct < 2; ++ct)
#pragma unroll
        for (int kc = 0; kc < 4; ++kc) {
            bf16x8 s;
#pragma unroll
            for (int jj = 0; jj < 8; ++jj)
                s[jj] = kLDS[(kc * 32 + kg * 8 + jj) * KS2 + w * 32 + ct * 16 + n];
            bfr[ct][kc] = s;
        }

#pragma unroll
    for (int mt = 0; mt < 4; ++mt) {
        const __bf16* ab = aLDS + (mt * 16 + n) * AS + kg * 8;
        bf16x8 a0 = *(const bf16x8*)(ab + 0);
        bf16x8 a1 = *(const bf16x8*)(ab + 32);
        bf16x8 a2 = *(const bf16x8*)(ab + 64);
        bf16x8 a3 = *(const bf16x8*)(ab + 96);
#pragma unroll
        for (int ct = 0; ct < 2; ++ct) {
            float bv = ct ? bv1 : bv0;
            floatx4 acc = {bv, bv, bv, bv};
            acc = MFMA16(a0, bfr[ct][0], acc);
            acc = MFMA16(a1, bfr[ct][1], acc);
            acc = MFMA16(a2, bfr[ct][2], acc);
            acc = MFMA16(a3, bfr[ct][3], acc);
#pragma unroll
            for (int r = 0; r < 4; ++r) {
                int v = v0 + mt * 16 + kg * 4 + r;
                if (v < V_) embk[(long)v * G_ + n0 + w * 32 + ct * 16 + n] = acc[r];
            }
        }
    }
}

// ---------------------------------------------------------------------------
// Kernel B (R14): R6 schedule with TWO waves per block (128 threads, 16 rows).
// Wave w owns 128 gate-cols: tiles (g, c2) -> cols g*64 + w*32 + c2*16 + [0,16)
// => 16 MFMA/step/wave, 8 cells/lane (c[8], static indices). The per-step
// barrier now syncs only 2 waves: max-of-2 arrival skew and half the
// post-release LDS read burst, 80x. R12 showed gate-work halving is ~free
// (latency-bound) -> doubling per-wave work should be nearly free too; the
// asymmetric payoff is the wave-count term of the barrier.
// Per-output accumulation order (xk C-init -> 2 chained h-MFMAs) identical
// to R6 -> bit-identical output.
// ---------------------------------------------------------------------------
template<int SEL, int RB, int WB>
__device__ __forceinline__ void lstm_step(
        int tt, int n, int kg, int w, int lane,
        const int* __restrict__ tokLDS,
        __bf16 (&hbuf)[2][16 * S_H],
        float (&xstage)[3][16 * XS],
        const bf16x8 (&afr)[4][2][2],
        const float* __restrict__ embk,
        float (&c)[8]) {
    // consumer reads: h^T_{t-1} (full K=64) + xk_t (this wave's 128 cols)
    const __bf16* hb = &hbuf[SEL ^ 1][0];
    bf16x8 hb0 = *(const bf16x8*)(hb + n * S_H + kg * 8);
    bf16x8 hb1 = *(const bf16x8*)(hb + n * S_H + 32 + kg * 8);
    const float* xrow = &xstage[RB][0] + n * XS + w * 32 + kg * 4;
    floatx4 acc[4][2];
#pragma unroll
    for (int g = 0; g < 4; ++g)
#pragma unroll
        for (int c2 = 0; c2 < 2; ++c2)
            acc[g][c2] = *(const floatx4*)(xrow + g * 64 + c2 * 16);

    // producer: DMA xk(t+2) rows w*8..w*8+7 into xstage[WB] (fire-and-forget)
#pragma unroll
    for (int j = 0; j < 8; ++j) {
        int tok = tokLDS[(w * 8 + j) * TS + tt];
        gload16(embk + (long)tok * G_ + (lane << 2),
                &xstage[WB][0] + (w * 8 + j) * XS);
    }

    // z^T tiles: acc[g][c2] += r1^T @ h^T  (same order as R6 -> bit-identical)
#pragma unroll
    for (int g = 0; g < 4; ++g)
#pragma unroll
        for (int c2 = 0; c2 < 2; ++c2) {
            acc[g][c2] = MFMA16(afr[g][c2][0], hb0, acc[g][c2]);
            acc[g][c2] = MFMA16(afr[g][c2][1], hb1, acc[g][c2]);
        }

    // gates: 8 cells/lane: (row n, unit w*32 + c2*16 + kg*4 + r)
#pragma unroll
    for (int c2 = 0; c2 < 2; ++c2) {
        bf16x4 hv;
#pragma unroll
        for (int r = 0; r < 4; ++r) {
            float zi = acc[0][c2][r], zf = acc[1][c2][r];
            float zg = acc[2][c2][r], zo = acc[3][c2][r];
            float cn = fmaf(sigmoidf_(zf), c[c2 * 4 + r], sigmoidf_(zi) * tanhf_(zg));
            float hn = sigmoidf_(zo) * tanhf_(cn);
            c[c2 * 4 + r] = cn;
            hv[r] = (__bf16)hn;
        }
        *(bf16x4*)(&hbuf[SEL][0] + n * S_H + w * 32 + c2 * 16 + kg * 4) = hv;
    }

    // LDS drained; only this step's 8 DMA loads may remain in flight.
    asm volatile("s_waitcnt lgkmcnt(0) vmcnt(8)\n\ts_barrier" ::: "memory");
}

__global__ __launch_bounds__(128) void lstm_kernel(const int*   __restrict__ tokens,
                                                   const float* __restrict__ embk,
                                                   const float* __restrict__ r1,
                                                   const float* __restrict__ Wd,
                                                   const float* __restrict__ bd,
                                                   float* __restrict__ out) {
    __shared__ int    tokLDS[16 * TS];       // 5.2 KB
    __shared__ __bf16 hbuf[2][16 * S_H];     // 4.6 KB
    __shared__ float  xstage[3][16 * XS];    // 49.9 KB (3-phase rotation)

    const int tid  = threadIdx.x;            // 0..127
    const int lane = tid & 63;
    const int w    = tid >> 6;               // wave 0/1: owns cols w*32+[0,32) per gate
    const int n    = lane & 15;              // batch row (N-operand of MFMA)
    const int kg   = lane >> 4;              // 0..3
    const int bb   = blockIdx.x * 16;

    for (int i = tid; i < 16 * T_; i += 128)
        tokLDS[(i / T_) * TS + (i % T_)] = tokens[bb * T_ + i];
    for (int i = tid; i < 2 * 16 * S_H; i += 128) (&hbuf[0][0])[i] = (__bf16)0.f;

    // A-fragments = r1^T (static): tile (g,c2) covers gate-cols
    // g*64 + w*32 + c2*16 + m;  A[m][k] with m=n, k = kc*32 + kg*8 + jj
    bf16x8 afr[4][2][2];
#pragma unroll
    for (int g = 0; g < 4; ++g)
#pragma unroll
        for (int c2 = 0; c2 < 2; ++c2)
#pragma unroll
            for (int kc = 0; kc < 2; ++kc) {
                bf16x8 s;
#pragma unroll
                for (int jj = 0; jj < 8; ++jj)
                    s[jj] = (__bf16)r1[(kc * 32 + kg * 8 + jj) * G_
                                       + g * 64 + w * 32 + c2 * 16 + n];
                afr[g][c2][kc] = s;
            }

    float c[8] = {0.f, 0.f, 0.f, 0.f, 0.f, 0.f, 0.f, 0.f};

    __syncthreads();      // tokens/hbuf visible; clean vmcnt base

    // prologue: DMA xstage[0] (t=0) then xstage[1] (t=1); wait oldest 8 done.
#pragma unroll
    for (int s = 0; s < 2; ++s)
#pragma unroll
        for (int j = 0; j < 8; ++j) {
            int tok = tokLDS[(w * 8 + j) * TS + s];
            gload16(embk + (long)tok * G_ + (lane << 2),
                    &xstage[s][0] + (w * 8 + j) * XS);
        }
    asm volatile("s_waitcnt lgkmcnt(0) vmcnt(8)\n\ts_barrier" ::: "memory");

    // 78 = 13*6 steps (lcm of buffer period 3, parity 2), then 2 tail steps.
    for (int t = 0; t < 78; t += 6) {
        lstm_step<0, 0, 2>(t + 2, n, kg, w, lane, tokLDS, hbuf, xstage, afr, embk, c);
        lstm_step<1, 1, 0>(t + 3, n, kg, w, lane, tokLDS, hbuf, xstage, afr, embk, c);
        lstm_step<0, 2, 1>(t + 4, n, kg, w, lane, tokLDS, hbuf, xstage, afr, embk, c);
        lstm_step<1, 0, 2>(t + 5, n, kg, w, lane, tokLDS, hbuf, xstage, afr, embk, c);
        lstm_step<0, 1, 0>(t + 6, n, kg, w, lane, tokLDS, hbuf, xstage, afr, embk, c);
        lstm_step<1, 2, 1>(t + 7, n, kg, w, lane, tokLDS, hbuf, xstage, afr, embk, c);
    }
    lstm_step<0, 0, 2>(79, n, kg, w, lane, tokLDS, hbuf, xstage, afr, embk, c); // t=78
    lstm_step<1, 1, 0>(79, n, kg, w, lane, tokLDS, hbuf, xstage, afr, embk, c); // t=79

    // drain remaining DMA before the epilogue reads LDS
    asm volatile("s_waitcnt vmcnt(0)" ::: "memory");

    // out[b] = sigmoid(h_final[b] . Wd + bd); h_79 in hbuf[1]
    if (tid < 16) {
        const __bf16* hb = hbuf[1] + tid * S_H;
        float s = bd[0];
#pragma unroll
        for (int u = 0; u < U_; ++u) s = fmaf((float)hb[u], Wd[u], s);
        out[bb + tid] = sigmoidf_(s);
    }
}

// ---------------------------------------------------------------------------
extern "C" void kernel_launch(void* const* d_in, const int* in_sizes, int n_in,
                              void* d_out, int out_size, void* d_ws, size_t ws_size,
                              hipStream_t stream) {
    const int*   tokens = (const int*)  d_in[0];
    const float* emb    = (const float*)d_in[1];
    // d_in[2..4] = k0, r0, b0 : dead in the reference (cell0 state unused)
    const float* k1     = (const float*)d_in[5];
    const float* r1     = (const float*)d_in[6];
    const float* b1     = (const float*)d_in[7];
    const float* Wd     = (const float*)d_in[8];
    const float* bd     = (const float*)d_in[9];
    float*       out    = (float*)d_out;

    float* embk = (float*)d_ws;              // V_*G_ floats = 10.24 MB

    embk_kernel<<<((V_ + 63) / 64) * 2, 256, 0, stream>>>(emb, k1, b1, embk);
    lstm_kernel<<<B_ / 16, 128, 0, stream>>>(tokens, embk, r1, Wd, bd, out);
}

// Round 15
// 134.646 us; speedup vs baseline: 1.2538x; 1.2538x over previous
//
#include <hip/hip_runtime.h>
#include <hip/hip_bf16.h>
#include <stdint.h>

// Problem constants
#define B_  4096
#define T_  80
#define E_  100
#define U_  64
#define G_  256    // 4*U
#define V_  10000

#define S_H  72    // hbuf row stride (bf16): 144B rows; b128 reads at the bank floor
#define AS   136   // embk emb-tile LDS stride (bf16)
#define KS2  132   // embk k1-tile ROW-major LDS stride (bf16)
#define TS   81    // token LDS row stride (ints); odd stride spreads rows across banks
#define XS   260   // xstage row stride (floats): consumer b128 reads at bank group
                   // (n+kg+4w)&7 -> uniform 8 lanes/group = conflict-free floor

typedef __attribute__((ext_vector_type(8))) __bf16 bf16x8;
typedef __attribute__((ext_vector_type(4))) __bf16 bf16x4;
typedef __attribute__((ext_vector_type(4))) float  floatx4;

__device__ __forceinline__ float sigmoidf_(float x) {
    return __builtin_amdgcn_rcpf(1.f + __expf(-x));
}

__device__ __forceinline__ float tanhf_(float x) {
    // 1 - 2/(e^{2x}+1): monotone, saturates correctly, no NaN
    return fmaf(-2.f, __builtin_amdgcn_rcpf(__expf(2.f * x) + 1.f), 1.f);
}

// global -> LDS direct DMA: each lane contributes 16B; LDS dest = wave-uniform
// base + lane*16 (linear). Tracked by vmcnt.
__device__ __forceinline__ void gload16(const float* gsrc, const float* ldst) {
    __builtin_amdgcn_global_load_lds(
        (const __attribute__((address_space(1))) void*)(uintptr_t)gsrc,
        (__attribute__((address_space(3))) void*)(uintptr_t)ldst,
        16, 0, 0);
}

#define MFMA16(A,B,C) __builtin_amdgcn_mfma_f32_16x16x32_bf16(A, B, C, 0, 0, 0)

// ---------------------------------------------------------------------------
// Kernel A (MFMA): embk[v][g] = b1[g] + emb[v] . k1[:,g]   (R5, known-good)
// k1 staged ROW-major in LDS (coalesced float4 reads -> bank-floor b64
// writes); B-fragments via 64 one-time ds_read_u16 (<=2-way banking).
// ---------------------------------------------------------------------------
__global__ __launch_bounds__(256) void embk_kernel(const float* __restrict__ emb,
                                                   const float* __restrict__ k1,
                                                   const float* __restrict__ b1,
                                                   float* __restrict__ embk) {
    __shared__ __bf16 aLDS[64 * AS];         // 17.4 KB  (emb tile, row-major)
    __shared__ __bf16 kLDS[128 * KS2];       // 33.8 KB  (k1 tile, ROW-major [k][col])

    const int tid  = threadIdx.x;
    const int lane = tid & 63;
    const int w    = tid >> 6;
    const int n    = lane & 15;
    const int kg   = lane >> 4;
    const int v0   = (blockIdx.x >> 1) * 64;
    const int n0   = (blockIdx.x & 1) * 128;
    const int nrows = min(64, V_ - v0);

    for (int i = tid; i < 64 * AS / 8; i += 256) {
        bf16x8 z;
#pragma unroll
        for (int jj = 0; jj < 8; ++jj) z[jj] = (__bf16)0.f;
        *(bf16x8*)(aLDS + i * 8) = z;
    }
    for (int i = tid; i < 28 * KS2; i += 256)
        kLDS[100 * KS2 + i] = (__bf16)0.f;

    const float bv0 = b1[n0 + w * 32 + n];
    const float bv1 = b1[n0 + w * 32 + 16 + n];

    __syncthreads();

    for (int i = tid; i < nrows * 25; i += 256) {
        int r = i / 25, q = i - r * 25;
        float4 ev = *(const float4*)(emb + (long)(v0 + r) * E_ + q * 4);
        bf16x4 bv; bv[0] = (__bf16)ev.x; bv[1] = (__bf16)ev.y;
                   bv[2] = (__bf16)ev.z; bv[3] = (__bf16)ev.w;
        *(bf16x4*)(aLDS + r * AS + q * 4) = bv;
    }
    for (int i = tid; i < 100 * 32; i += 256) {
        int k = i >> 5, cq = (i & 31) * 4;
        float4 kv = *(const float4*)(k1 + (long)k * G_ + n0 + cq);
        bf16x4 bv; bv[0] = (__bf16)kv.x; bv[1] = (__bf16)kv.y;
                   bv[2] = (__bf16)kv.z; bv[3] = (__bf16)kv.w;
        *(bf16x4*)(kLDS + k * KS2 + cq) = bv;
    }
    __syncthreads();

    bf16x8 bfr[2][4];
#pragma unroll
    for (int ct = 0; ct < 2; ++ct)
#pragma unroll
        for (int kc = 0; kc < 4; ++kc) {
            bf16x8 s;
#pragma unroll
            for (int jj = 0; jj < 8; ++jj)
                s[jj] = kLDS[(kc * 32 + kg * 8 + jj) * KS2 + w * 32 + ct * 16 + n];
            bfr[ct][kc] = s;
        }

#pragma unroll
    for (int mt = 0; mt < 4; ++mt) {
        const __bf16* ab = aLDS + (mt * 16 + n) * AS + kg * 8;
        bf16x8 a0 = *(const bf16x8*)(ab + 0);
        bf16x8 a1 = *(const bf16x8*)(ab + 32);
        bf16x8 a2 = *(const bf16x8*)(ab + 64);
        bf16x8 a3 = *(const bf16x8*)(ab + 96);
#pragma unroll
        for (int ct = 0; ct < 2; ++ct) {
            float bv = ct ? bv1 : bv0;
            floatx4 acc = {bv, bv, bv, bv};
            acc = MFMA16(a0, bfr[ct][0], acc);
            acc = MFMA16(a1, bfr[ct][1], acc);
            acc = MFMA16(a2, bfr[ct][2], acc);
            acc = MFMA16(a3, bfr[ct][3], acc);
#pragma unroll
            for (int r = 0; r < 4; ++r) {
                int v = v0 + mt * 16 + kg * 4 + r;
                if (v < V_) embk[(long)v * G_ + n0 + w * 32 + ct * 16 + n] = acc[r];
            }
        }
    }
}

// ---------------------------------------------------------------------------
// Kernel B (R6-exact, measured best 56.8 us; structural optimum of the
// barrier'd split — every neighbor variant benched R7-R14 and lost).
// Per step:
//   - consume xstage[RB] (4x ds_read_b128) + h^T_{t-1} (2x ds_read_b128)
//   - issue 4x global_load_lds: row (w*4+j) of xk(t+2) -> xstage[WB]
//     (64 lanes x 16B contiguous per instr: fully coalesced)
//   - 8 MFMA (z^T = r1^T h^T + xk, C-init = DMA'd xk), gates, h b64 write
//   - s_waitcnt lgkmcnt(0) vmcnt(4) + s_barrier (counted vmcnt, never 0)
// ---------------------------------------------------------------------------
template<int SEL, int RB, int WB>
__device__ __forceinline__ void lstm_step(
        int tt, int n, int kg, int w, int lane,
        const int* __restrict__ tokLDS,
        __bf16 (&hbuf)[2][16 * S_H],
        float (&xstage)[3][16 * XS],
        const bf16x8 (&afr)[4][2],
        const float* __restrict__ embk,
        float (&c)[4]) {
    // consumer reads: h^T_{t-1} + xk_t
    const __bf16* hb = &hbuf[SEL ^ 1][0];
    bf16x8 hb0 = *(const bf16x8*)(hb + n * S_H + kg * 8);
    bf16x8 hb1 = *(const bf16x8*)(hb + n * S_H + 32 + kg * 8);
    const float* xrow = &xstage[RB][0] + n * XS + w * 16 + kg * 4;
    floatx4 a0 = *(const floatx4*)(xrow + 0);
    floatx4 a1 = *(const floatx4*)(xrow + 64);
    floatx4 a2 = *(const floatx4*)(xrow + 128);
    floatx4 a3 = *(const floatx4*)(xrow + 192);

    // producer: DMA xk(t+2) rows w*4..w*4+3 into xstage[WB] (fire-and-forget)
#pragma unroll
    for (int j = 0; j < 4; ++j) {
        int tok = tokLDS[(w * 4 + j) * TS + tt];
        gload16(embk + (long)tok * G_ + (lane << 2),
                &xstage[WB][0] + (w * 4 + j) * XS);
    }

    // z^T tiles: acc[ct] = r1^T @ h^T + xk
    a0 = MFMA16(afr[0][0], hb0, a0);  a0 = MFMA16(afr[0][1], hb1, a0);
    a1 = MFMA16(afr[1][0], hb0, a1);  a1 = MFMA16(afr[1][1], hb1, a1);
    a2 = MFMA16(afr[2][0], hb0, a2);  a2 = MFMA16(afr[2][1], hb1, a2);
    a3 = MFMA16(afr[3][0], hb0, a3);  a3 = MFMA16(afr[3][1], hb1, a3);

    // gates: 4 dense cells/lane; a0=i, a1=f, a2=g, a3=o
    bf16x4 hv;
#pragma unroll
    for (int r = 0; r < 4; ++r) {
        float zi = a0[r], zf = a1[r], zg = a2[r], zo = a3[r];
        float cn = fmaf(sigmoidf_(zf), c[r], sigmoidf_(zi) * tanhf_(zg));
        float hn = sigmoidf_(zo) * tanhf_(cn);
        c[r] = cn;
        hv[r] = (__bf16)hn;
    }
    // h_new: 4 consecutive units -> one b64 write
    *(bf16x4*)(&hbuf[SEL][0] + n * S_H + w * 16 + kg * 4) = hv;

    // LDS drained; only this step's 4 DMA loads may remain in flight.
    asm volatile("s_waitcnt lgkmcnt(0) vmcnt(4)\n\ts_barrier" ::: "memory");
}

__global__ __launch_bounds__(256) void lstm_kernel(const int*   __restrict__ tokens,
                                                   const float* __restrict__ embk,
                                                   const float* __restrict__ r1,
                                                   const float* __restrict__ Wd,
                                                   const float* __restrict__ bd,
                                                   float* __restrict__ out) {
    __shared__ int    tokLDS[16 * TS];       // 5.2 KB
    __shared__ __bf16 hbuf[2][16 * S_H];     // 4.6 KB
    __shared__ float  xstage[3][16 * XS];    // 49.9 KB (3-phase rotation)

    const int tid  = threadIdx.x;
    const int lane = tid & 63;
    const int w    = tid >> 6;               // unit block [w*16, w*16+16)
    const int n    = lane & 15;              // batch row (N-operand of MFMA)
    const int kg   = lane >> 4;              // 0..3
    const int bb   = blockIdx.x * 16;

    for (int i = tid; i < 16 * T_; i += 256)
        tokLDS[(i / T_) * TS + (i % T_)] = tokens[bb * T_ + i];
    for (int i = tid; i < 2 * 16 * S_H; i += 256) (&hbuf[0][0])[i] = (__bf16)0.f;

    // A-fragments = r1^T (static): tile ct covers gate-cols ct*64 + w*16 + m
    bf16x8 afr[4][2];
#pragma unroll
    for (int ct = 0; ct < 4; ++ct)
#pragma unroll
        for (int kc = 0; kc < 2; ++kc) {
            bf16x8 s;
#pragma unroll
            for (int jj = 0; jj < 8; ++jj)
                s[jj] = (__bf16)r1[(kc * 32 + kg * 8 + jj) * G_ + ct * 64 + w * 16 + n];
            afr[ct][kc] = s;
        }

    float c[4] = {0.f, 0.f, 0.f, 0.f};

    __syncthreads();      // tokens/hbuf visible; clean vmcnt base

    // prologue: DMA xstage[0] (t=0) then xstage[1] (t=1); wait oldest 4 done.
#pragma unroll
    for (int s = 0; s < 2; ++s)
#pragma unroll
        for (int j = 0; j < 4; ++j) {
            int tok = tokLDS[(w * 4 + j) * TS + s];
            gload16(embk + (long)tok * G_ + (lane << 2),
                    &xstage[s][0] + (w * 4 + j) * XS);
        }
    asm volatile("s_waitcnt lgkmcnt(0) vmcnt(4)\n\ts_barrier" ::: "memory");

    // 78 = 13*6 steps (lcm of buffer period 3, parity 2), then 2 tail steps.
    // In-loop tt = t+2 never exceeds 79.
    for (int t = 0; t < 78; t += 6) {
        lstm_step<0, 0, 2>(t + 2, n, kg, w, lane, tokLDS, hbuf, xstage, afr, embk, c);
        lstm_step<1, 1, 0>(t + 3, n, kg, w, lane, tokLDS, hbuf, xstage, afr, embk, c);
        lstm_step<0, 2, 1>(t + 4, n, kg, w, lane, tokLDS, hbuf, xstage, afr, embk, c);
        lstm_step<1, 0, 2>(t + 5, n, kg, w, lane, tokLDS, hbuf, xstage, afr, embk, c);
        lstm_step<0, 1, 0>(t + 6, n, kg, w, lane, tokLDS, hbuf, xstage, afr, embk, c);
        lstm_step<1, 2, 1>(t + 7, n, kg, w, lane, tokLDS, hbuf, xstage, afr, embk, c);
    }
    lstm_step<0, 0, 2>(79, n, kg, w, lane, tokLDS, hbuf, xstage, afr, embk, c); // t=78
    lstm_step<1, 1, 0>(79, n, kg, w, lane, tokLDS, hbuf, xstage, afr, embk, c); // t=79

    // drain remaining DMA before the epilogue reads LDS
    asm volatile("s_waitcnt vmcnt(0)" ::: "memory");

    // out[b] = sigmoid(h_final[b] . Wd + bd); h_79 in hbuf[1]
    if (tid < 16) {
        const __bf16* hb = hbuf[1] + tid * S_H;
        float s = bd[0];
#pragma unroll
        for (int u = 0; u < U_; ++u) s = fmaf((float)hb[u], Wd[u], s);
        out[bb + tid] = sigmoidf_(s);
    }
}

// ---------------------------------------------------------------------------
extern "C" void kernel_launch(void* const* d_in, const int* in_sizes, int n_in,
                              void* d_out, int out_size, void* d_ws, size_t ws_size,
                              hipStream_t stream) {
    const int*   tokens = (const int*)  d_in[0];
    const float* emb    = (const float*)d_in[1];
    // d_in[2..4] = k0, r0, b0 : dead in the reference (cell0 state unused)
    const float* k1     = (const float*)d_in[5];
    const float* r1     = (const float*)d_in[6];
    const float* b1     = (const float*)d_in[7];
    const float* Wd     = (const float*)d_in[8];
    const float* bd     = (const float*)d_in[9];
    float*       out    = (float*)d_out;

    float* embk = (float*)d_ws;              // V_*G_ floats = 10.24 MB

    embk_kernel<<<((V_ + 63) / 64) * 2, 256, 0, stream>>>(emb, k1, b1, embk);
    lstm_kernel<<<B_ / 16, 256, 0, stream>>>(tokens, embk, r1, Wd, bd, out);
}